// Round 8
// baseline (3071.730 us; speedup 1.0000x reference)
//
#include <hip/hip_runtime.h>
#include <hip/hip_fp16.h>

#define B_  16
#define T_  400
#define F_  512
#define U_  1024
#define G4_ 4096
#define NBLK 256

typedef __attribute__((ext_vector_type(8))) short short8;
typedef __attribute__((ext_vector_type(4))) float f32x4;

__device__ __forceinline__ unsigned bf16bits(float f) {
  unsigned u = __float_as_uint(f);
  return (u + 0x7fffu + ((u >> 16) & 1u)) >> 16;   // RNE f32->bf16
}
__device__ __forceinline__ float sigm(float x)   { return 1.f/(1.f + __expf(-x)); }
__device__ __forceinline__ float tanh_f(float x) { return 2.f/(1.f + __expf(-2.f*x)) - 1.f; }

__device__ __forceinline__ unsigned ald(const unsigned* p) {
  return __hip_atomic_load(p, __ATOMIC_RELAXED, __HIP_MEMORY_SCOPE_AGENT);
}
__device__ __forceinline__ void ast(unsigned* p, unsigned v) {
  __hip_atomic_store(p, v, __ATOMIC_RELAXED, __HIP_MEMORY_SCOPE_AGENT);
}
// coherent 16B load (bypass L1/L2 -> coherence point); caller must waitcnt.
__device__ __forceinline__ uint4 ald4(const unsigned* p) {
  uint4 v;
  asm volatile("global_load_dwordx4 %0, %1, off sc0 sc1" : "=v"(v) : "v"(p));
  return v;
}
// pack hi16 of two tagged dwords into one dword (bf16 pair, k then k+1)
__device__ __forceinline__ unsigned pk(unsigned lo_d, unsigned hi_d) {
  return __builtin_amdgcn_perm(hi_d, lo_d, 0x07060302);
}

// ---------------- Phase 1: xw[dir] = x @ k_dir + b_dir (MFMA bf16) -------
__global__ __launch_bounds__(256) void gemm_xw(
    const float* __restrict__ X,
    const float* __restrict__ Kf, const float* __restrict__ Kb,
    const float* __restrict__ Bf, const float* __restrict__ Bb,
    __half* __restrict__ xwf, __half* __restrict__ xwb)
{
  const int dir = blockIdx.z;
  const float* Km   = dir ? Kb : Kf;
  const float* bias = dir ? Bb : Bf;
  __half* outp      = dir ? xwb : xwf;
  const int m0 = blockIdx.x * 64;
  const int n0 = blockIdx.y * 64;
  const int tid = threadIdx.x, wid = tid >> 6, lane = tid & 63;

  __shared__ unsigned short A_bf[64*40];
  __shared__ unsigned short B_bf[64*40];

  const int wm = wid >> 1, wn = wid & 1;
  const int arow = lane & 15, kgrp = lane >> 4;
  const int sm = tid & 63, skoct = tid >> 6;

  f32x4 acc00 = {0.f,0.f,0.f,0.f}, acc01 = {0.f,0.f,0.f,0.f};
  f32x4 acc10 = {0.f,0.f,0.f,0.f}, acc11 = {0.f,0.f,0.f,0.f};

  for (int k0 = 0; k0 < F_; k0 += 32) {
    {
      const float* xp = &X[(size_t)(m0+sm)*F_ + k0 + skoct*8];
      const float4 v0 = *reinterpret_cast<const float4*>(xp);
      const float4 v1 = *reinterpret_cast<const float4*>(xp + 4);
      short8 t;
      t[0]=(short)bf16bits(v0.x); t[1]=(short)bf16bits(v0.y);
      t[2]=(short)bf16bits(v0.z); t[3]=(short)bf16bits(v0.w);
      t[4]=(short)bf16bits(v1.x); t[5]=(short)bf16bits(v1.y);
      t[6]=(short)bf16bits(v1.z); t[7]=(short)bf16bits(v1.w);
      *reinterpret_cast<short8*>(&A_bf[sm*40 + skoct*8]) = t;
    }
    {
      short8 t;
      #pragma unroll
      for (int j = 0; j < 8; ++j)
        t[j] = (short)bf16bits(Km[(size_t)(k0+skoct*8+j)*G4_ + n0 + sm]);
      *reinterpret_cast<short8*>(&B_bf[sm*40 + skoct*8]) = t;
    }
    __syncthreads();
    const short8 a0 = *reinterpret_cast<const short8*>(&A_bf[(wm*32 + arow)*40      + kgrp*8]);
    const short8 a1 = *reinterpret_cast<const short8*>(&A_bf[(wm*32 + 16 + arow)*40 + kgrp*8]);
    const short8 b0 = *reinterpret_cast<const short8*>(&B_bf[(wn*32 + arow)*40      + kgrp*8]);
    const short8 b1 = *reinterpret_cast<const short8*>(&B_bf[(wn*32 + 16 + arow)*40 + kgrp*8]);
    acc00 = __builtin_amdgcn_mfma_f32_16x16x32_bf16(a0, b0, acc00, 0, 0, 0);
    acc01 = __builtin_amdgcn_mfma_f32_16x16x32_bf16(a0, b1, acc01, 0, 0, 0);
    acc10 = __builtin_amdgcn_mfma_f32_16x16x32_bf16(a1, b0, acc10, 0, 0, 0);
    acc11 = __builtin_amdgcn_mfma_f32_16x16x32_bf16(a1, b1, acc11, 0, 0, 0);
    __syncthreads();
  }
  #pragma unroll
  for (int tm = 0; tm < 2; ++tm) {
    #pragma unroll
    for (int tn = 0; tn < 2; ++tn) {
      const f32x4 a = tm ? (tn ? acc11 : acc10) : (tn ? acc01 : acc00);
      const int n = n0 + wn*32 + tn*16 + arow;
      const float bv = bias[n];
      #pragma unroll
      for (int r = 0; r < 4; ++r) {
        const int m = m0 + wm*32 + tm*16 + kgrp*4 + r;
        outp[(size_t)m*G4_ + n] = __float2half_rn(a[r] + bv);
      }
    }
  }
}

// ---------------- Phase 2: persistent interleaved bidir LSTM (MFMA) ------
// 256 WGs x 256 threads; WG owns u-slice [wg*4, wg*4+4) of BOTH directions.
// Superstep s = phase A (dir0) then phase B (dir1): each dir's exchange
// latency hides under the other dir's phase. r_bf cols: [dir*16 + gate*4+uu].
// h: tagged dwords hw2[par][dir][b][u] = (bf16<<16)|(s+1); flags are hints,
// tags are correctness (ack-free producer). Reduce: wave0=dir0, wave1=dir1.
__global__ __launch_bounds__(256, 1) void lstm_rec(
    const __half* __restrict__ xwf, const __half* __restrict__ xwb,
    const float* __restrict__ Rf, const float* __restrict__ Rb,
    const float* __restrict__ gammav, const float* __restrict__ betav,
    const float* __restrict__ mmean, const float* __restrict__ mvar,
    unsigned* __restrict__ hw2,     // [par2][dir2][16][1024] tagged dwords
    float* __restrict__ outp,       // [16][400][2048] f32
    unsigned* __restrict__ flags)   // [dir2][256] monotonic hints
{
  __shared__ unsigned short r_bf[32*1040];     // 66560 B  [c][k] bf16
  __shared__ float z_s[2][4*528];              // 16896 B  [phase][wave][16][33]
  // total 83456 B > 80K -> guaranteed 1 WG/CU

  const int wg = blockIdx.x;
  const int u4 = wg * 4;
  const int tid = threadIdx.x, wid = tid >> 6, lane = tid & 63;

  // stage r for BOTH dirs: col c = dir*16 + gate*4 + uu
  {
    const int c4   = (tid & 7) * 4;            // {0,4,...,28}
    const int d    = c4 >> 4;
    const int gate = (c4 >> 2) & 3;
    const int kb   = (tid >> 3) * 32;
    const float* R = d ? Rb : Rf;
    const int gcol = gate*U_ + u4;
    for (int kk = 0; kk < 32; ++kk) {
      const float4 rv = *reinterpret_cast<const float4*>(&R[(size_t)(kb+kk)*G4_ + gcol]);
      r_bf[(c4+0)*1040 + kb+kk] = (unsigned short)bf16bits(rv.x);
      r_bf[(c4+1)*1040 + kb+kk] = (unsigned short)bf16bits(rv.y);
      r_bf[(c4+2)*1040 + kb+kk] = (unsigned short)bf16bits(rv.z);
      r_bf[(c4+3)*1040 + kb+kk] = (unsigned short)bf16bits(rv.w);
    }
  }

  // BN constants + cell state per phase-group (wave0: dir0, wave1: dir1)
  float inv0=0.f, add0=0.f, cst0=0.f, inv1=0.f, add1=0.f, cst1=0.f;
  if (tid < 64) {
    const int j = u4 + (tid & 3);
    inv0 = gammav[j] * rsqrtf(mvar[j] + 1e-3f);
    add0 = betav[j] - mmean[j]*inv0;
    ast(&hw2[(size_t)(0*2 + 0)*16384 + (tid>>2)*1024 + u4 + (tid&3)], 1u);
  } else if (tid < 128) {
    const int lt = tid - 64;
    const int j = U_ + u4 + (lt & 3);
    inv1 = gammav[j] * rsqrtf(mvar[j] + 1e-3f);
    add1 = betav[j] - mmean[j]*inv1;
    ast(&hw2[(size_t)(0*2 + 1)*16384 + (lt>>2)*1024 + u4 + (lt&3)], 1u);
  }
  __syncthreads();
  if (tid == 0)  ast(&flags[wg], 1u);
  if (tid == 64) ast(&flags[256 + wg], 1u);

  // MFMA fragment addressing + B-fragment preload (loop-invariant registers)
  const int arow = lane & 15;                  // A row = batch; B row = col
  const int kgrp = lane >> 4;
  const unsigned short* bpa = &r_bf[arow*1040 + wid*256];          // dir0 cols
  const unsigned short* bpb = &r_bf[(16 + arow)*1040 + wid*256];   // dir1 cols
  #define LB(P, K) (*reinterpret_cast<const short8*>(&(P)[(K)*32 + kgrp*8]))
  const short8 rbA0 = LB(bpa,0), rbA1 = LB(bpa,1), rbA2 = LB(bpa,2), rbA3 = LB(bpa,3);
  const short8 rbA4 = LB(bpa,4), rbA5 = LB(bpa,5), rbA6 = LB(bpa,6), rbA7 = LB(bpa,7);
  const short8 rbB0 = LB(bpb,0), rbB1 = LB(bpb,1), rbB2 = LB(bpb,2), rbB3 = LB(bpb,3);
  const short8 rbB4 = LB(bpb,4), rbB5 = LB(bpb,5), rbB6 = LB(bpb,6), rbB7 = LB(bpb,7);
  #undef LB
  const size_t hfrag_off = (size_t)arow*1024 + wid*256 + kgrp*8;

  #define FRAG(QA, QB, RB) { \
    uint4 av; \
    av.x = pk(QA.x, QA.y); av.y = pk(QA.z, QA.w); \
    av.z = pk(QB.x, QB.y); av.w = pk(QB.z, QB.w); \
    const short8 a = *reinterpret_cast<const short8*>(&av); \
    acc = __builtin_amdgcn_mfma_f32_16x16x32_bf16(a, RB, acc, 0, 0, 0); }
  #define CK4(Q) (((Q.x&0xffffu)^tgt)|((Q.y&0xffffu)^tgt)|((Q.z&0xffffu)^tgt)|((Q.w&0xffffu)^tgt))

  // one phase: dir D, B-fragments RBP#, reduce group at LOBASE, time index TIN
  #define PHASE(D, RBP, CST, XI, XF, XG, XO, INVV, ADDV, LOBASE, TIN)              \
  {                                                                                \
    const unsigned tgt = (unsigned)(s + 1);                                        \
    const unsigned* flp = &flags[(D)*256 + wid*64 + lane];                         \
    for (;;) {                                                                     \
      const unsigned f = ald(flp);                                                 \
      if (__all((int)(f >= tgt))) break;                                           \
      __builtin_amdgcn_s_sleep(1);                                                 \
    }                                                                              \
    const unsigned* hgp = hw2 + (size_t)((s&1)*2 + (D))*16384 + hfrag_off;         \
    uint4 q0,q1,q2,q3,q4,q5,q6,q7,q8,q9,q10,q11,q12,q13,q14,q15;                   \
    for (;;) {                                                                     \
      q0  = ald4(hgp +   0); q1  = ald4(hgp +   4);                                \
      q2  = ald4(hgp +  32); q3  = ald4(hgp +  36);                                \
      q4  = ald4(hgp +  64); q5  = ald4(hgp +  68);                                \
      q6  = ald4(hgp +  96); q7  = ald4(hgp + 100);                                \
      q8  = ald4(hgp + 128); q9  = ald4(hgp + 132);                                \
      q10 = ald4(hgp + 160); q11 = ald4(hgp + 164);                                \
      q12 = ald4(hgp + 192); q13 = ald4(hgp + 196);                                \
      q14 = ald4(hgp + 224); q15 = ald4(hgp + 228);                                \
      asm volatile("s_waitcnt vmcnt(0)" ::: "memory");                             \
      const unsigned mism = CK4(q0)|CK4(q1)|CK4(q2)|CK4(q3)|CK4(q4)|CK4(q5)        \
                          |CK4(q6)|CK4(q7)|CK4(q8)|CK4(q9)|CK4(q10)|CK4(q11)       \
                          |CK4(q12)|CK4(q13)|CK4(q14)|CK4(q15);                    \
      if (__all((int)(mism == 0u))) break;                                         \
      __builtin_amdgcn_s_sleep(1);                                                 \
    }                                                                              \
    __builtin_amdgcn_sched_barrier(0);                                             \
    f32x4 acc = {0.f,0.f,0.f,0.f};                                                 \
    FRAG(q0,q1,  RBP##0) FRAG(q2,q3,  RBP##1) FRAG(q4,q5,  RBP##2)                 \
    FRAG(q6,q7,  RBP##3) FRAG(q8,q9,  RBP##4) FRAG(q10,q11,RBP##5)                 \
    FRAG(q12,q13,RBP##6) FRAG(q14,q15,RBP##7)                                      \
    {                                                                              \
      const int col = lane & 15, rbase = kgrp*4;                                   \
      float* zw = &z_s[D][wid*528];                                                \
      zw[(rbase+0)*33 + col] = acc[0]; zw[(rbase+1)*33 + col] = acc[1];            \
      zw[(rbase+2)*33 + col] = acc[2]; zw[(rbase+3)*33 + col] = acc[3];            \
    }                                                                              \
    __syncthreads();                                                               \
    if ((tid & ~63) == (LOBASE)) {                                                 \
      const int lt = tid - (LOBASE); const int b = lt >> 2; const int uu = lt & 3; \
      float zi = (XI), zf = (XF), zg = (XG), zo = (XO);                            \
      const float* zr = &z_s[D][b*33 + uu];                                        \
      zi += zr[0]  + zr[528]  + zr[1056] + zr[1584];                               \
      zf += zr[4]  + zr[532]  + zr[1060] + zr[1588];                               \
      zg += zr[8]  + zr[536]  + zr[1064] + zr[1592];                               \
      zo += zr[12] + zr[540]  + zr[1068] + zr[1596];                               \
      const float ig = sigm(zi), fg = sigm(zf), og = sigm(zo);                     \
      const float gg = tanh_f(zg);                                                 \
      (CST) = fg*(CST) + ig*gg;                                                    \
      const float hv = og * tanh_f(CST);                                           \
      ast(&hw2[(size_t)(((s+1)&1)*2 + (D))*16384 + b*1024 + u4 + uu],              \
          (bf16bits(hv) << 16) | (unsigned)(s + 2));                               \
      asm volatile("" ::: "memory");                                               \
      if (tid == (LOBASE)) ast(&flags[(D)*256 + wg], (unsigned)(s + 2));           \
      outp[((size_t)b*T_ + (TIN))*2048 + (D)*U_ + u4 + uu] = hv*(INVV) + (ADDV);   \
    }                                                                              \
  }

  for (int s = 0; s < T_; ++s) {
    // xw prefetch for both phases (plain cached loads, issued up front)
    float x0i=0.f,x0f=0.f,x0g=0.f,x0o=0.f, x1i=0.f,x1f=0.f,x1g=0.f,x1o=0.f;
    if (tid < 64) {
      const __half* xp = &xwf[((size_t)(tid>>2)*T_ + s)*G4_ + u4 + (tid&3)];
      x0i = __half2float(xp[0]);    x0f = __half2float(xp[1024]);
      x0g = __half2float(xp[2048]); x0o = __half2float(xp[3072]);
    } else if (tid < 128) {
      const int lt = tid - 64;
      const __half* xp = &xwb[((size_t)(lt>>2)*T_ + (T_-1-s))*G4_ + u4 + (lt&3)];
      x1i = __half2float(xp[0]);    x1f = __half2float(xp[1024]);
      x1g = __half2float(xp[2048]); x1o = __half2float(xp[3072]);
    }

    PHASE(0, rbA, cst0, x0i, x0f, x0g, x0o, inv0, add0, 0,  s)
    PHASE(1, rbB, cst1, x1i, x1f, x1g, x1o, inv1, add1, 64, (T_-1-s))
  }
  #undef PHASE
  #undef FRAG
  #undef CK4
}

extern "C" void kernel_launch(void* const* d_in, const int* in_sizes, int n_in,
                              void* d_out, int out_size, void* d_ws, size_t ws_size,
                              hipStream_t stream)
{
  const float* x  = (const float*)d_in[0];
  const float* kf = (const float*)d_in[1];
  const float* rf = (const float*)d_in[2];
  const float* bf = (const float*)d_in[3];
  const float* kb = (const float*)d_in[4];
  const float* rb = (const float*)d_in[5];
  const float* bb = (const float*)d_in[6];
  const float* ga = (const float*)d_in[7];
  const float* be = (const float*)d_in[8];
  const float* mm = (const float*)d_in[9];
  const float* mv = (const float*)d_in[10];
  float* outp = (float*)d_out;

  // ws: [flags 4KB][hw2 tagged dwords 512KB][xwf f16][xwb f16]
  unsigned* flags = (unsigned*)d_ws;
  unsigned* hw2   = (unsigned*)((char*)d_ws + 4096);
  __half* xwf     = (__half*)((char*)d_ws + 4096 + 524288);
  __half* xwb     = xwf + (size_t)6400*G4_;

  hipMemsetAsync(flags, 0, 4096, stream);
  gemm_xw<<<dim3(100, 64, 2), dim3(256), 0, stream>>>(x, kf, kb, bf, bb, xwf, xwb);
  lstm_rec<<<dim3(NBLK), dim3(256), 0, stream>>>(xwf, xwb, rf, rb, ga, be, mm, mv,
                                                 hw2, outp, flags);
}

// Round 9
// 2296.632 us; speedup vs baseline: 1.3375x; 1.3375x over previous
//
#include <hip/hip_runtime.h>
#include <hip/hip_fp16.h>

#define B_  16
#define T_  400
#define F_  512
#define U_  1024
#define G4_ 4096
#define NBLK 256

typedef __attribute__((ext_vector_type(8))) short short8;
typedef __attribute__((ext_vector_type(4))) float f32x4;

__device__ __forceinline__ unsigned bf16bits(float f) {
  unsigned u = __float_as_uint(f);
  return (u + 0x7fffu + ((u >> 16) & 1u)) >> 16;   // RNE f32->bf16
}
__device__ __forceinline__ float sigm(float x)   { return 1.f/(1.f + __expf(-x)); }
__device__ __forceinline__ float tanh_f(float x) { return 2.f/(1.f + __expf(-2.f*x)) - 1.f; }

__device__ __forceinline__ void ast(unsigned* p, unsigned v) {
  __hip_atomic_store(p, v, __ATOMIC_RELAXED, __HIP_MEMORY_SCOPE_AGENT);
}
// coherent 16B load (bypass L1/L2 -> coherence point); caller must waitcnt.
__device__ __forceinline__ uint4 ald4(const unsigned* p) {
  uint4 v;
  asm volatile("global_load_dwordx4 %0, %1, off sc0 sc1" : "=v"(v) : "v"(p));
  return v;
}
// pack hi16 of two tagged dwords into one dword (bf16 pair, k then k+1)
__device__ __forceinline__ unsigned pk(unsigned lo_d, unsigned hi_d) {
  return __builtin_amdgcn_perm(hi_d, lo_d, 0x07060302);
}

// ---------------- Phase 1: xw[dir] = x @ k_dir + b_dir (MFMA bf16) -------
__global__ __launch_bounds__(256) void gemm_xw(
    const float* __restrict__ X,
    const float* __restrict__ Kf, const float* __restrict__ Kb,
    const float* __restrict__ Bf, const float* __restrict__ Bb,
    __half* __restrict__ xwf, __half* __restrict__ xwb)
{
  const int dir = blockIdx.z;
  const float* Km   = dir ? Kb : Kf;
  const float* bias = dir ? Bb : Bf;
  __half* outp      = dir ? xwb : xwf;
  const int m0 = blockIdx.x * 64;
  const int n0 = blockIdx.y * 64;
  const int tid = threadIdx.x, wid = tid >> 6, lane = tid & 63;

  __shared__ unsigned short A_bf[64*40];
  __shared__ unsigned short B_bf[64*40];

  const int wm = wid >> 1, wn = wid & 1;
  const int arow = lane & 15, kgrp = lane >> 4;
  const int sm = tid & 63, skoct = tid >> 6;

  f32x4 acc00 = {0.f,0.f,0.f,0.f}, acc01 = {0.f,0.f,0.f,0.f};
  f32x4 acc10 = {0.f,0.f,0.f,0.f}, acc11 = {0.f,0.f,0.f,0.f};

  for (int k0 = 0; k0 < F_; k0 += 32) {
    {
      const float* xp = &X[(size_t)(m0+sm)*F_ + k0 + skoct*8];
      const float4 v0 = *reinterpret_cast<const float4*>(xp);
      const float4 v1 = *reinterpret_cast<const float4*>(xp + 4);
      short8 t;
      t[0]=(short)bf16bits(v0.x); t[1]=(short)bf16bits(v0.y);
      t[2]=(short)bf16bits(v0.z); t[3]=(short)bf16bits(v0.w);
      t[4]=(short)bf16bits(v1.x); t[5]=(short)bf16bits(v1.y);
      t[6]=(short)bf16bits(v1.z); t[7]=(short)bf16bits(v1.w);
      *reinterpret_cast<short8*>(&A_bf[sm*40 + skoct*8]) = t;
    }
    {
      short8 t;
      #pragma unroll
      for (int j = 0; j < 8; ++j)
        t[j] = (short)bf16bits(Km[(size_t)(k0+skoct*8+j)*G4_ + n0 + sm]);
      *reinterpret_cast<short8*>(&B_bf[sm*40 + skoct*8]) = t;
    }
    __syncthreads();
    const short8 a0 = *reinterpret_cast<const short8*>(&A_bf[(wm*32 + arow)*40      + kgrp*8]);
    const short8 a1 = *reinterpret_cast<const short8*>(&A_bf[(wm*32 + 16 + arow)*40 + kgrp*8]);
    const short8 b0 = *reinterpret_cast<const short8*>(&B_bf[(wn*32 + arow)*40      + kgrp*8]);
    const short8 b1 = *reinterpret_cast<const short8*>(&B_bf[(wn*32 + 16 + arow)*40 + kgrp*8]);
    acc00 = __builtin_amdgcn_mfma_f32_16x16x32_bf16(a0, b0, acc00, 0, 0, 0);
    acc01 = __builtin_amdgcn_mfma_f32_16x16x32_bf16(a0, b1, acc01, 0, 0, 0);
    acc10 = __builtin_amdgcn_mfma_f32_16x16x32_bf16(a1, b0, acc10, 0, 0, 0);
    acc11 = __builtin_amdgcn_mfma_f32_16x16x32_bf16(a1, b1, acc11, 0, 0, 0);
    __syncthreads();
  }
  #pragma unroll
  for (int tm = 0; tm < 2; ++tm) {
    #pragma unroll
    for (int tn = 0; tn < 2; ++tn) {
      const f32x4 a = tm ? (tn ? acc11 : acc10) : (tn ? acc01 : acc00);
      const int n = n0 + wn*32 + tn*16 + arow;
      const float bv = bias[n];
      #pragma unroll
      for (int r = 0; r < 4; ++r) {
        const int m = m0 + wm*32 + tm*16 + kgrp*4 + r;
        outp[(size_t)m*G4_ + n] = __float2half_rn(a[r] + bv);
      }
    }
  }
}

// ---------------- Phase 2: persistent bidirectional LSTM (MFMA) ----------
// h exchange: SELF-TAGGED dwords hw2[par][dir][b][u] = (bf16(h)<<16)|(s+1).
// No flags, no acks. Consumers poll a 1-dwordx4/lane SAMPLE that covers all
// 32 quarter-producers (the sample IS data -> no flag-ahead-of-data race),
// then do the full fragment load validated by tags (expected ~0 retries).
__global__ __launch_bounds__(256, 1) void lstm_rec(
    const __half* __restrict__ xwf, const __half* __restrict__ xwb,
    const float* __restrict__ Rf, const float* __restrict__ Rb,
    const float* __restrict__ gammav, const float* __restrict__ betav,
    const float* __restrict__ mmean, const float* __restrict__ mvar,
    unsigned* __restrict__ hw2,     // [par2][dir2][16][1024] tagged dwords
    float* __restrict__ outp)       // [16][400][2048] f32
{
  __shared__ unsigned short r_bf[32*1040];     // 66560 B  [c][k] bf16
  __shared__ float z_s[2][4*528];              // 16896 B  [par][wave][16][33]
  // total 83456 B > 80K -> guaranteed 1 WG/CU

  const int wg  = blockIdx.x;
  const int dir = wg >> 7;
  const int u0  = (wg & 127) * 8;
  const __half* xw = dir ? xwb : xwf;
  const float*  R  = dir ? Rb  : Rf;
  const int tid  = threadIdx.x;
  const int wid  = tid >> 6;
  const int lane = tid & 63;

  // stage recurrent weights transposed: r_bf[c][k] = bf16(R[k][gc(c)])
  {
    const int c4 = (tid & 7) * 4;
    const int kb = (tid >> 3) * 32;
    const int gcol = ((c4 >> 3) * U_) + u0 + (c4 & 7);
    for (int kk = 0; kk < 32; ++kk) {
      const float4 rv = *reinterpret_cast<const float4*>(&R[(size_t)(kb+kk)*G4_ + gcol]);
      r_bf[(c4+0)*1040 + kb+kk] = (unsigned short)bf16bits(rv.x);
      r_bf[(c4+1)*1040 + kb+kk] = (unsigned short)bf16bits(rv.y);
      r_bf[(c4+2)*1040 + kb+kk] = (unsigned short)bf16bits(rv.z);
      r_bf[(c4+3)*1040 + kb+kk] = (unsigned short)bf16bits(rv.w);
    }
  }

  float inv = 0.f, add = 0.f, cst = 0.f;
  const int gb = tid >> 3, uu = tid & 7;       // reduce-thread mapping (tid<128)
  if (tid < 128) {
    const int j = dir*U_ + u0 + uu;
    inv = gammav[j] * rsqrtf(mvar[j] + 1e-3f);
    add = betav[j] - mmean[j]*inv;
    // h(0) = 0, tag 1, parity 0 (overwrites poison/leftover; consumers spin
    // on tags, so no cross-WG init barrier is needed)
    ast(&hw2[(size_t)((0*2 + dir)*16 + gb)*1024 + u0 + uu], 1u);
  }
  __syncthreads();                             // r_bf staged

  // MFMA fragment addressing + B-fragment preload (registers, loop-invariant)
  const int arow = lane & 15;                  // batch
  const int kgrp = lane >> 4;
  const unsigned short* bc0 = &r_bf[arow*1040 + wid*256];
  const unsigned short* bc1 = &r_bf[(16 + arow)*1040 + wid*256];
  #define LB(P, K) (*reinterpret_cast<const short8*>(&(P)[(K)*32 + kgrp*8]))
  const short8 rb00 = LB(bc0,0), rb01 = LB(bc0,1), rb02 = LB(bc0,2), rb03 = LB(bc0,3);
  const short8 rb04 = LB(bc0,4), rb05 = LB(bc0,5), rb06 = LB(bc0,6), rb07 = LB(bc0,7);
  const short8 rb10 = LB(bc1,0), rb11 = LB(bc1,1), rb12 = LB(bc1,2), rb13 = LB(bc1,3);
  const short8 rb14 = LB(bc1,4), rb15 = LB(bc1,5), rb16 = LB(bc1,6), rb17 = LB(bc1,7);
  #undef LB
  const size_t hfrag_off = (size_t)arow*1024 + wid*256 + kgrp*8;
  // sample: lane covers u-block (lane&31) of this wave's quarter, batch (lane>>5)*8
  const size_t samp_off = (size_t)((lane >> 5)*8)*1024 + wid*256 + (lane & 31)*8;

  for (int s = 0; s < T_; ++s) {
    const int tin = dir ? (T_-1-s) : s;

    // xw prefetch (plain cached loads, issued pre-poll)
    float xv0=0.f, xv1=0.f, xv2=0.f, xv3=0.f;
    if (tid < 128) {
      const __half* xp = &xw[((size_t)gb*T_ + tin)*G4_ + u0 + uu];
      xv0 = __half2float(xp[0]);    xv1 = __half2float(xp[1024]);
      xv2 = __half2float(xp[2048]); xv3 = __half2float(xp[3072]);
    }

    const unsigned tgt = (unsigned)(s + 1);
    const size_t pbase = (size_t)((s&1)*2 + dir)*16384;
    #define CK4(Q) (((Q.x&0xffffu)^tgt)|((Q.y&0xffffu)^tgt)|((Q.z&0xffffu)^tgt)|((Q.w&0xffffu)^tgt))

    // cheap sample poll: one dwordx4 per lane, all 32 quarter-producers covered
    {
      const unsigned* sp = hw2 + pbase + samp_off;
      for (;;) {
        const uint4 t = ald4(sp);
        asm volatile("s_waitcnt vmcnt(0)" ::: "memory");
        if (__all((int)(CK4(t) == 0u))) break;
        __builtin_amdgcn_s_sleep(1);
      }
    }

    // full fragment load, tag-validated (expected ~0 retries)
    const unsigned* hgp = hw2 + pbase + hfrag_off;
    uint4 q0,q1,q2,q3,q4,q5,q6,q7,q8,q9,q10,q11,q12,q13,q14,q15;
    for (;;) {
      q0  = ald4(hgp +   0); q1  = ald4(hgp +   4);
      q2  = ald4(hgp +  32); q3  = ald4(hgp +  36);
      q4  = ald4(hgp +  64); q5  = ald4(hgp +  68);
      q6  = ald4(hgp +  96); q7  = ald4(hgp + 100);
      q8  = ald4(hgp + 128); q9  = ald4(hgp + 132);
      q10 = ald4(hgp + 160); q11 = ald4(hgp + 164);
      q12 = ald4(hgp + 192); q13 = ald4(hgp + 196);
      q14 = ald4(hgp + 224); q15 = ald4(hgp + 228);
      asm volatile("s_waitcnt vmcnt(0)" ::: "memory");
      const unsigned mism = CK4(q0)|CK4(q1)|CK4(q2)|CK4(q3)|CK4(q4)|CK4(q5)|CK4(q6)|CK4(q7)
                          | CK4(q8)|CK4(q9)|CK4(q10)|CK4(q11)|CK4(q12)|CK4(q13)|CK4(q14)|CK4(q15);
      if (__all((int)(mism == 0u))) break;
      __builtin_amdgcn_s_sleep(1);
    }
    #undef CK4
    __builtin_amdgcn_sched_barrier(0);

    // unpack + MFMA (8 fragments x 2 col-tiles)
    f32x4 acc0 = {0.f,0.f,0.f,0.f}, acc1 = {0.f,0.f,0.f,0.f};
    #define FRAG(QA, QB, RB0, RB1) { \
      uint4 av; \
      av.x = pk(QA.x, QA.y); av.y = pk(QA.z, QA.w); \
      av.z = pk(QB.x, QB.y); av.w = pk(QB.z, QB.w); \
      const short8 a = *reinterpret_cast<const short8*>(&av); \
      acc0 = __builtin_amdgcn_mfma_f32_16x16x32_bf16(a, RB0, acc0, 0, 0, 0); \
      acc1 = __builtin_amdgcn_mfma_f32_16x16x32_bf16(a, RB1, acc1, 0, 0, 0); }
    FRAG(q0, q1, rb00, rb10) FRAG(q2, q3, rb01, rb11)
    FRAG(q4, q5, rb02, rb12) FRAG(q6, q7, rb03, rb13)
    FRAG(q8, q9, rb04, rb14) FRAG(q10,q11,rb05, rb15)
    FRAG(q12,q13,rb06, rb16) FRAG(q14,q15,rb07, rb17)
    #undef FRAG

    // z partials: D col=lane&15 (gate-col), row=kgrp*4+reg (batch)
    {
      const int col = lane & 15, rbase = kgrp*4;
      float* zw = &z_s[s&1][wid*528];
      #pragma unroll
      for (int r = 0; r < 4; ++r) {
        zw[(rbase+r)*33 + col]      = acc0[r];
        zw[(rbase+r)*33 + 16 + col] = acc1[r];
      }
    }
    __syncthreads();                           // all 4 waves' z(s) complete

    // reduce + gates + tagged h store (fire-and-forget) + outp
    if (tid < 128) {
      float zi = xv0, zf = xv1, zg = xv2, zo = xv3;
      #pragma unroll
      for (int w = 0; w < 4; ++w) {
        const float* zr = &z_s[s&1][w*528 + gb*33];
        zi += zr[uu]; zf += zr[8+uu]; zg += zr[16+uu]; zo += zr[24+uu];
      }
      const float ig = sigm(zi), fg = sigm(zf), og = sigm(zo);
      const float gg = tanh_f(zg);
      cst = fg*cst + ig*gg;
      const float hv = og * tanh_f(cst);
      ast(&hw2[(size_t)((((s+1)&1)*2 + dir)*16 + gb)*1024 + u0 + uu],
          (bf16bits(hv) << 16) | (unsigned)(s + 2));
      outp[((size_t)gb*T_ + tin)*2048 + dir*U_ + u0 + uu] = hv*inv + add;
    }
    // no second barrier: z_s parity double-buffered
  }
}

extern "C" void kernel_launch(void* const* d_in, const int* in_sizes, int n_in,
                              void* d_out, int out_size, void* d_ws, size_t ws_size,
                              hipStream_t stream)
{
  const float* x  = (const float*)d_in[0];
  const float* kf = (const float*)d_in[1];
  const float* rf = (const float*)d_in[2];
  const float* bf = (const float*)d_in[3];
  const float* kb = (const float*)d_in[4];
  const float* rb = (const float*)d_in[5];
  const float* bb = (const float*)d_in[6];
  const float* ga = (const float*)d_in[7];
  const float* be = (const float*)d_in[8];
  const float* mm = (const float*)d_in[9];
  const float* mv = (const float*)d_in[10];
  float* outp = (float*)d_out;

  // ws: [hw2 tagged dwords 2par*2dir*16*1024*4B = 512KB][xwf f16][xwb f16]
  unsigned* hw2 = (unsigned*)d_ws;
  __half* xwf   = (__half*)((char*)d_ws + 524288);
  __half* xwb   = xwf + (size_t)6400*G4_;

  gemm_xw<<<dim3(100, 64, 2), dim3(256), 0, stream>>>(x, kf, kb, bf, bb, xwf, xwb);
  lstm_rec<<<dim3(NBLK), dim3(256), 0, stream>>>(xwf, xwb, rf, rb, ga, be, mm, mv,
                                                 hw2, outp);
}